// Round 1
// baseline (1665.987 us; speedup 1.0000x reference)
//
#include <hip/hip_runtime.h>

#define HH 512
#define WW 512
#define NHH 32
#define NWW 32
#define NSP 1024
#define NB 4
#define CIN 128
#define CO 8
#define NITER 5

// ---------------- Conv 3x3 (128->8) + bias + ReLU, NCHW, zero pad ----------------
__global__ __launch_bounds__(256) void conv_relu_kernel(
    const float* __restrict__ feat, const float* __restrict__ wconv,
    const float* __restrict__ bconv, float* __restrict__ featall)
{
    __shared__ float ws[CO * CIN * 9];   // 36 KB, OIHW order
    int t = threadIdx.x;
    for (int i = t; i < CO * CIN * 9; i += 256) ws[i] = wconv[i];
    __syncthreads();

    int blk = blockIdx.x;                // grid = NB * HH * 2
    int xb = blk & 1;
    int y  = (blk >> 1) & (HH - 1);
    int b  = blk >> 10;
    int x  = xb * 256 + t;

    float acc[CO];
#pragma unroll
    for (int o = 0; o < CO; ++o) acc[o] = 0.f;

    const float* fb = feat + (size_t)b * CIN * HH * WW;
    for (int c = 0; c < CIN; ++c) {
        const float* fc = fb + (size_t)c * HH * WW;
        float v[9];
#pragma unroll
        for (int ky = 0; ky < 3; ++ky) {
            int yy = y + ky - 1;
            bool yok = (yy >= 0) && (yy < HH);
#pragma unroll
            for (int kx = 0; kx < 3; ++kx) {
                int xx = x + kx - 1;
                bool ok = yok && (xx >= 0) && (xx < WW);
                v[ky * 3 + kx] = ok ? fc[(size_t)yy * WW + xx] : 0.f;
            }
        }
#pragma unroll
        for (int o = 0; o < CO; ++o) {
            const float* wc = &ws[(o * CIN + c) * 9];
            float a = acc[o];
#pragma unroll
            for (int k = 0; k < 9; ++k) a = fmaf(v[k], wc[k], a);
            acc[o] = a;
        }
    }
    size_t obase = ((size_t)b * CO) * HH * WW + (size_t)y * WW + x;
#pragma unroll
    for (int o = 0; o < CO; ++o)
        featall[obase + (size_t)o * HH * WW] = fmaxf(acc[o] + bconv[o], 0.f);
}

// ---------------- Initial superpixel means: mean over each 16x16 tile ----------------
__global__ __launch_bounds__(256) void init_spf_kernel(
    const float* __restrict__ featall, float* __restrict__ spf)
{
    int blk = blockIdx.x;                // NB * NSP
    int s = blk & (NSP - 1);
    int b = blk >> 10;
    int sy = s >> 5, sx = s & 31;
    int t = threadIdx.x;
    int ty = t >> 4, tx = t & 15;
    int y = sy * 16 + ty, x = sx * 16 + tx;

    size_t base = ((size_t)b * CO) * HH * WW + (size_t)y * WW + x;
    float f[CO];
#pragma unroll
    for (int c = 0; c < CO; ++c) f[c] = featall[base + (size_t)c * HH * WW];

#pragma unroll
    for (int off = 1; off < 64; off <<= 1)
#pragma unroll
        for (int c = 0; c < CO; ++c) f[c] += __shfl_xor(f[c], off, 64);

    __shared__ float lds[4][CO];
    int wave = t >> 6, lane = t & 63;
    if (lane == 0)
#pragma unroll
        for (int c = 0; c < CO; ++c) lds[wave][c] = f[c];
    __syncthreads();
    if (t < CO) {
        float sum = lds[0][t] + lds[1][t] + lds[2][t] + lds[3][t];
        spf[((size_t)b * CO + t) * NSP + s] = sum * (1.0f / 256.0f);
    }
}

// ---------------- One EM iteration: nd -> softmax -> Q, accumulate num/den ----------------
__global__ __launch_bounds__(256) void iter_kernel(
    const float* __restrict__ featall, const float* __restrict__ spf,
    float* __restrict__ num, float* __restrict__ den,
    float* __restrict__ qout, int write_q)
{
    int blk = blockIdx.x;                // NB * NSP
    int s = blk & (NSP - 1);
    int b = blk >> 10;
    int sy = s >> 5, sx = s & 31;
    int t = threadIdx.x;
    int ty = t >> 4, tx = t & 15;
    int y = sy * 16 + ty, x = sx * 16 + tx;

    int nidx[9]; bool nval[9];
#pragma unroll
    for (int k = 0; k < 9; ++k) {
        int ny = sy + k / 3 - 1;
        int nx = sx + (k % 3) - 1;
        nval[k] = (ny >= 0) && (ny < NHH) && (nx >= 0) && (nx < NWW);
        int cy = min(max(ny, 0), NHH - 1), cx = min(max(nx, 0), NWW - 1);
        nidx[k] = cy * NWW + cx;
    }

    __shared__ float sg[9][CO];          // gathered spf for the 9 neighbors
    if (t < 72) {
        int k = t >> 3, c = t & 7;
        sg[k][c] = spf[((size_t)b * CO + c) * NSP + nidx[k]];
    }
    __syncthreads();

    size_t fbase = ((size_t)b * CO) * HH * WW + (size_t)y * WW + x;
    float f[CO];
#pragma unroll
    for (int c = 0; c < CO; ++c) f[c] = featall[fbase + (size_t)c * HH * WW];

    float nd[9];
#pragma unroll
    for (int k = 0; k < 9; ++k) {
        float d = 0.f;
#pragma unroll
        for (int c = 0; c < CO; ++c) { float df = f[c] - sg[k][c]; d = fmaf(df, df, d); }
        nd[k] = -d;
    }
    float m = -1e30f;
#pragma unroll
    for (int k = 0; k < 9; ++k) m = nval[k] ? fmaxf(m, nd[k]) : m;
    float e[9], esum = 0.f;
#pragma unroll
    for (int k = 0; k < 9; ++k) {
        e[k] = nval[k] ? __expf(nd[k] - m) : 0.f;
        esum += e[k];
    }
    float inv = 1.0f / esum;
#pragma unroll
    for (int k = 0; k < 9; ++k) e[k] *= inv;   // == Q (invalid entries exactly 0) == Qm

    if (write_q) {
#pragma unroll
        for (int k = 0; k < 9; ++k)
            qout[(((size_t)b * 9 + k) * HH + y) * WW + x] = e[k];
    }

    // Block-reduce den(9) + num(72) then 81 global atomics.
    __shared__ float red[4][81];
    int lane = t & 63, wave = t >> 6;
#pragma unroll
    for (int k = 0; k < 9; ++k) {
        float v[9];
        v[0] = e[k];
#pragma unroll
        for (int c = 0; c < CO; ++c) v[c + 1] = f[c] * e[k];
#pragma unroll
        for (int off = 1; off < 64; off <<= 1) {
#pragma unroll
            for (int j = 0; j < 9; ++j) v[j] += __shfl_xor(v[j], off, 64);
        }
        if (lane == 0) {
#pragma unroll
            for (int j = 0; j < 9; ++j) red[wave][k * 9 + j] = v[j];
        }
    }
    __syncthreads();
    if (t < 81) {
        int k = t / 9, j = t % 9;
        if (nval[k]) {
            float v = red[0][t] + red[1][t] + red[2][t] + red[3][t];
            if (j == 0) unsafeAtomicAdd(&den[(size_t)b * NSP + nidx[k]], v);
            else        unsafeAtomicAdd(&num[((size_t)b * CO + (j - 1)) * NSP + nidx[k]], v);
        }
    }
}

// ---------------- spf = num / max(den, 1e-12) ----------------
__global__ __launch_bounds__(256) void update_spf_kernel(
    const float* __restrict__ num, const float* __restrict__ den,
    float* __restrict__ spf_out)
{
    int i = blockIdx.x * 256 + threadIdx.x;
    if (i >= NB * CO * NSP) return;
    int s = i & (NSP - 1);
    int b = (i >> 10) >> 3;
    spf_out[i] = num[i] / fmaxf(den[b * NSP + s], 1e-12f);
}

extern "C" void kernel_launch(void* const* d_in, const int* in_sizes, int n_in,
                              void* d_out, int out_size, void* d_ws, size_t ws_size,
                              hipStream_t stream)
{
    const float* feat  = (const float*)d_in[0];
    const float* wconv = (const float*)d_in[1];
    const float* bconv = (const float*)d_in[2];

    float* out     = (float*)d_out;
    float* qout    = out;                                  // (4,9,512,512)
    float* spf_out = out + (size_t)NB * 9 * HH * WW;       // (4,8,1024)
    float* featall = spf_out + (size_t)NB * CO * NSP;      // (4,8,512,512)

    float* spf = (float*)d_ws;                             // (4,8,1024)
    float* num = spf + (size_t)NB * CO * NSP;              // (4,8,1024)
    float* den = num + (size_t)NB * CO * NSP;              // (4,1024)

    conv_relu_kernel<<<NB * HH * 2, 256, 0, stream>>>(feat, wconv, bconv, featall);
    init_spf_kernel<<<NB * NSP, 256, 0, stream>>>(featall, spf);

    for (int it = 0; it < NITER; ++it) {
        hipMemsetAsync(num, 0, (size_t)(NB * CO * NSP + NB * NSP) * sizeof(float), stream);
        int last = (it == NITER - 1);
        iter_kernel<<<NB * NSP, 256, 0, stream>>>(featall, spf, num, den, qout, last);
        update_spf_kernel<<<(NB * CO * NSP + 255) / 256, 256, 0, stream>>>(
            num, den, last ? spf_out : spf);
    }
}

// Round 3
// 1485.608 us; speedup vs baseline: 1.1214x; 1.1214x over previous
//
#include <hip/hip_runtime.h>

#define HH 512
#define WW 512
#define NHH 32
#define NWW 32
#define NSP 1024
#define NB 4
#define CIN 128
#define CO 8
#define NITER 5

typedef short bf16x8 __attribute__((ext_vector_type(8)));
typedef float f32x4 __attribute__((ext_vector_type(4)));

__device__ inline short f2bf(float f) {
    union { float fv; unsigned u; } v; v.fv = f;
    unsigned r = v.u + 0x7FFF + ((v.u >> 16) & 1);   // RNE
    return (short)(r >> 16);
}

// ---------------- Conv 3x3 (128->8) + bias + ReLU via bf16 MFMA implicit GEMM ----
// Block: 256 thr (4 waves), tile 64x4 pixels. K = 128ch x 9taps, chunked 32 ch.
// LDS A: halo tile [6 rows][66 px][40 ch-slots(32+8 pad)] bf16, transposed so an
// A-frag (16 px x 8 contig ch) is one ds_read_b128. Taps = immediate offsets.
__global__ __launch_bounds__(256) void conv_mfma_kernel(
    const float* __restrict__ feat, const float* __restrict__ wconv,
    const float* __restrict__ bconv, float* __restrict__ featall)
{
    __shared__ __align__(16) short ldsA[6 * 66 * 40];   // 31680 B
    __shared__ __align__(16) short ldsB[9 * 16 * 32];   // 9216 B, [tap][o(16)][c(32)]

    int t  = threadIdx.x;
    int bx = blockIdx.x & 7;            // 8 tiles of 64 in x
    int by = (blockIdx.x >> 3) & 127;   // 128 tiles of 4 in y
    int b  = blockIdx.x >> 10;

    // zero B once (covers the o=8..15 zero-pad columns for every chunk)
    for (int i = t; i < 9 * 16 * 32 / 2; i += 256) ((int*)ldsB)[i] = 0;

    int lane = t & 63, w = t >> 6;      // wave w owns pixel row y = by*4 + w
    int row = lane & 15, q = lane >> 4; // MFMA A: row = M-idx, k = q*8 + j

    int abase[4];
#pragma unroll
    for (int m = 0; m < 4; ++m)         // lane base byte addr at tap (-1,-1)
        abase[m] = ((w * 66 + (m * 16 + row)) * 40 + q * 8) * 2;
    int bbase = (row * 32 + q * 8) * 2; // row = o here; + tap*1024 bytes

    f32x4 acc[4];
#pragma unroll
    for (int m = 0; m < 4; ++m) acc[m] = (f32x4)0.f;

    const int c_ld = t >> 3;            // staging: channel 0..31
    const int sub  = t & 7;             // staging: x-segment (9 px each)

    for (int chunk = 0; chunk < 4; ++chunk) {
        int c0 = chunk * 32;
        __syncthreads();                // previous chunk's compute done
        // ---- stage A (fp32 -> bf16, transpose to [y][x][c]) ----
        const float* fp = feat + (size_t)(b * CIN + c0 + c_ld) * (HH * WW);
#pragma unroll
        for (int yi = 0; yi < 6; ++yi) {
            int gy = by * 4 + yi - 1;
            bool yok = (unsigned)gy < HH;
#pragma unroll
            for (int i = 0; i < 9; ++i) {
                int xi = sub * 9 + i;
                if (xi < 66) {
                    int gx = bx * 64 + xi - 1;
                    float v = (yok && (unsigned)gx < WW) ? fp[(size_t)gy * WW + gx] : 0.f;
                    ldsA[(yi * 66 + xi) * 40 + c_ld] = f2bf(v);
                }
            }
        }
        // ---- stage B: w[o][c0+c][tap] -> ldsB[tap][o][c] ----
        for (int i = t; i < 9 * 8 * 32; i += 256) {
            int tap = i >> 8;
            int o   = (i >> 5) & 7;
            int c   = i & 31;
            ldsB[(tap * 16 + o) * 32 + c] = f2bf(wconv[(o * CIN + c0 + c) * 9 + tap]);
        }
        __syncthreads();

        // ---- 9 taps x 4 M-tiles MFMA ----
#pragma unroll
        for (int tap = 0; tap < 9; ++tap) {
            bf16x8 bfr = *(const bf16x8*)((const char*)ldsB + bbase + tap * 1024);
            int ky = tap / 3, kx = tap % 3;
            int off = (ky * 66 + kx) * 80;      // bytes; folds to ds imm offset
#pragma unroll
            for (int m = 0; m < 4; ++m) {
                bf16x8 afr = *(const bf16x8*)((const char*)ldsA + abase[m] + off);
                acc[m] = __builtin_amdgcn_mfma_f32_16x16x32_bf16(afr, bfr, acc[m], 0, 0, 0);
            }
        }
    }

    // ---- epilogue: bias + relu + store. D: o = lane&15, px-in-mtile = q*4+r ----
    int o = lane & 15;
    float bias = bconv[o & 7];
    int y = by * 4 + w;
#pragma unroll
    for (int m = 0; m < 4; ++m) {
#pragma unroll
        for (int r = 0; r < 4; ++r) {
            int x = bx * 64 + m * 16 + q * 4 + r;
            if (o < CO)
                featall[(((size_t)b * CO + o) * HH + y) * WW + x] =
                    fmaxf(acc[m][r] + bias, 0.f);
        }
    }
}

// ---------------- Initial superpixel means: mean over each 16x16 tile ----------------
__global__ __launch_bounds__(256) void init_spf_kernel(
    const float* __restrict__ featall, float* __restrict__ spf)
{
    int blk = blockIdx.x;                // NB * NSP
    int s = blk & (NSP - 1);
    int b = blk >> 10;
    int sy = s >> 5, sx = s & 31;
    int t = threadIdx.x;
    int ty = t >> 4, tx = t & 15;
    int y = sy * 16 + ty, x = sx * 16 + tx;

    size_t base = ((size_t)b * CO) * HH * WW + (size_t)y * WW + x;
    float f[CO];
#pragma unroll
    for (int c = 0; c < CO; ++c) f[c] = featall[base + (size_t)c * HH * WW];

#pragma unroll
    for (int off = 1; off < 64; off <<= 1)
#pragma unroll
        for (int c = 0; c < CO; ++c) f[c] += __shfl_xor(f[c], off, 64);

    __shared__ float lds[4][CO];
    int wave = t >> 6, lane = t & 63;
    if (lane == 0)
#pragma unroll
        for (int c = 0; c < CO; ++c) lds[wave][c] = f[c];
    __syncthreads();
    if (t < CO) {
        float sum = lds[0][t] + lds[1][t] + lds[2][t] + lds[3][t];
        spf[((size_t)b * CO + t) * NSP + s] = sum * (1.0f / 256.0f);
    }
}

// ---------------- One EM iteration: nd -> softmax -> Q, accumulate num/den ----------------
__global__ __launch_bounds__(256) void iter_kernel(
    const float* __restrict__ featall, const float* __restrict__ spf,
    float* __restrict__ num, float* __restrict__ den,
    float* __restrict__ qout, int write_q)
{
    int blk = blockIdx.x;                // NB * NSP
    int s = blk & (NSP - 1);
    int b = blk >> 10;
    int sy = s >> 5, sx = s & 31;
    int t = threadIdx.x;
    int ty = t >> 4, tx = t & 15;
    int y = sy * 16 + ty, x = sx * 16 + tx;

    int nidx[9]; bool nval[9];
#pragma unroll
    for (int k = 0; k < 9; ++k) {
        int ny = sy + k / 3 - 1;
        int nx = sx + (k % 3) - 1;
        nval[k] = (ny >= 0) && (ny < NHH) && (nx >= 0) && (nx < NWW);
        int cy = min(max(ny, 0), NHH - 1), cx = min(max(nx, 0), NWW - 1);
        nidx[k] = cy * NWW + cx;
    }

    __shared__ float sg[9][CO];          // gathered spf for the 9 neighbors
    if (t < 72) {
        int k = t >> 3, c = t & 7;
        sg[k][c] = spf[((size_t)b * CO + c) * NSP + nidx[k]];
    }
    __syncthreads();

    size_t fbase = ((size_t)b * CO) * HH * WW + (size_t)y * WW + x;
    float f[CO];
#pragma unroll
    for (int c = 0; c < CO; ++c) f[c] = featall[fbase + (size_t)c * HH * WW];

    float nd[9];
#pragma unroll
    for (int k = 0; k < 9; ++k) {
        float d = 0.f;
#pragma unroll
        for (int c = 0; c < CO; ++c) { float df = f[c] - sg[k][c]; d = fmaf(df, df, d); }
        nd[k] = -d;
    }
    float m = -1e30f;
#pragma unroll
    for (int k = 0; k < 9; ++k) m = nval[k] ? fmaxf(m, nd[k]) : m;
    float e[9], esum = 0.f;
#pragma unroll
    for (int k = 0; k < 9; ++k) {
        e[k] = nval[k] ? __expf(nd[k] - m) : 0.f;
        esum += e[k];
    }
    float inv = 1.0f / esum;
#pragma unroll
    for (int k = 0; k < 9; ++k) e[k] *= inv;   // == Q (invalid entries exactly 0) == Qm

    if (write_q) {
#pragma unroll
        for (int k = 0; k < 9; ++k)
            qout[(((size_t)b * 9 + k) * HH + y) * WW + x] = e[k];
    }

    // Block-reduce den(9) + num(72) then 81 global atomics.
    __shared__ float red[4][81];
    int lane = t & 63, wave = t >> 6;
#pragma unroll
    for (int k = 0; k < 9; ++k) {
        float v[9];
        v[0] = e[k];
#pragma unroll
        for (int c = 0; c < CO; ++c) v[c + 1] = f[c] * e[k];
#pragma unroll
        for (int off = 1; off < 64; off <<= 1) {
#pragma unroll
            for (int j = 0; j < 9; ++j) v[j] += __shfl_xor(v[j], off, 64);
        }
        if (lane == 0) {
#pragma unroll
            for (int j = 0; j < 9; ++j) red[wave][k * 9 + j] = v[j];
        }
    }
    __syncthreads();
    if (t < 81) {
        int k = t / 9, j = t % 9;
        if (nval[k]) {
            float v = red[0][t] + red[1][t] + red[2][t] + red[3][t];
            if (j == 0) unsafeAtomicAdd(&den[(size_t)b * NSP + nidx[k]], v);
            else        unsafeAtomicAdd(&num[((size_t)b * CO + (j - 1)) * NSP + nidx[k]], v);
        }
    }
}

// ---------------- spf = num / max(den, 1e-12) ----------------
__global__ __launch_bounds__(256) void update_spf_kernel(
    const float* __restrict__ num, const float* __restrict__ den,
    float* __restrict__ spf_out)
{
    int i = blockIdx.x * 256 + threadIdx.x;
    if (i >= NB * CO * NSP) return;
    int s = i & (NSP - 1);
    int b = (i >> 10) >> 3;
    spf_out[i] = num[i] / fmaxf(den[b * NSP + s], 1e-12f);
}

extern "C" void kernel_launch(void* const* d_in, const int* in_sizes, int n_in,
                              void* d_out, int out_size, void* d_ws, size_t ws_size,
                              hipStream_t stream)
{
    const float* feat  = (const float*)d_in[0];
    const float* wconv = (const float*)d_in[1];
    const float* bconv = (const float*)d_in[2];

    float* out     = (float*)d_out;
    float* qout    = out;                                  // (4,9,512,512)
    float* spf_out = out + (size_t)NB * 9 * HH * WW;       // (4,8,1024)
    float* featall = spf_out + (size_t)NB * CO * NSP;      // (4,8,512,512)

    float* spf = (float*)d_ws;                             // (4,8,1024)
    float* num = spf + (size_t)NB * CO * NSP;              // (4,8,1024)
    float* den = num + (size_t)NB * CO * NSP;              // (4,1024)

    conv_mfma_kernel<<<NB * 8 * 128, 256, 0, stream>>>(feat, wconv, bconv, featall);
    init_spf_kernel<<<NB * NSP, 256, 0, stream>>>(featall, spf);

    for (int it = 0; it < NITER; ++it) {
        hipMemsetAsync(num, 0, (size_t)(NB * CO * NSP + NB * NSP) * sizeof(float), stream);
        int last = (it == NITER - 1);
        iter_kernel<<<NB * NSP, 256, 0, stream>>>(featall, spf, num, den, qout, last);
        update_spf_kernel<<<(NB * CO * NSP + 255) / 256, 256, 0, stream>>>(
            num, den, last ? spf_out : spf);
    }
}